// Round 7
// baseline (1550.694 us; speedup 1.0000x reference)
//
#include <hip/hip_runtime.h>
#include <math.h>

#define N_NODES 6144
#define KCL 20
#define NE 98304
#define RPT 12      // rows per thread in the sequential kernel (512 thr)
#define MIDT 512

// ---------------- workspace layout (bytes) ----------------
#define OFF_T        0ull          // 122880 f32 (zeroed)
#define OFF_BITMAP   491520ull     // 4718592 B bitmap (zeroed)
#define OFF_COLSUM0  5210112ull    // 20 f32 (zeroed)
#define OFF_CSG      5210192ull    // 20 f32 (zeroed)
#define OFF_CSFIN    5210272ull    // 20 f32 (zeroed)
#define OFF_DACC     5210368ull    // 4 doubles (zeroed)
#define ZERO_BYTES   5210400ull
#define OFF_LOGITS   5210624ull    // 6144*20 f32 row-major
#define OFF_UCM      5702144ull    // 6144*20 f32 column-major (unscaled S)
#define OFF_SW       6193664ull    // 6144*20 f32 row-major (final S)
#define OFF_XE       6685184ull    // 6144*256 f32
#define OFF_TROW     12976640ull   // 6144 f32
#define OFF_GOUT     13001216ull   // 6144 f32

// ---------------- MLP: logits ----------------
__global__ __launch_bounds__(128) void k_mlp(const float* __restrict__ x,
    const float* __restrict__ W1, const float* __restrict__ b1,
    const float* __restrict__ W2, const float* __restrict__ b2,
    const float* __restrict__ W3, const float* __restrict__ b3,
    float* __restrict__ logits){
  __shared__ float xs[16][256];
  __shared__ float h1[16][128];
  __shared__ float h2[16][64];
  const int tid = threadIdx.x;
  const int r0 = blockIdx.x * 16;
  for (int idx = tid; idx < 16*256; idx += 128){ int u = idx >> 8, i = idx & 255; xs[u][i] = x[(r0+u)*256 + i]; }
  __syncthreads();
  {
    float acc[16]; float bb = b1[tid];
    #pragma unroll
    for (int u=0;u<16;u++) acc[u]=bb;
    for (int i=0;i<256;i++){ float wv = W1[i*128+tid];
      #pragma unroll
      for (int u=0;u<16;u++) acc[u]=fmaf(xs[u][i], wv, acc[u]); }
    #pragma unroll
    for (int u=0;u<16;u++) h1[u][tid]=fmaxf(acc[u],0.f);
  }
  __syncthreads();
  if (tid < 64){
    float acc[16]; float bb = b2[tid];
    #pragma unroll
    for (int u=0;u<16;u++) acc[u]=bb;
    for (int i=0;i<128;i++){ float wv = W2[i*64+tid];
      #pragma unroll
      for (int u=0;u<16;u++) acc[u]=fmaf(h1[u][i], wv, acc[u]); }
    #pragma unroll
    for (int u=0;u<16;u++) h2[u][tid]=fmaxf(acc[u],0.f);
  }
  __syncthreads();
  if (tid < 20){
    float acc[16]; float bb = b3[tid];
    #pragma unroll
    for (int u=0;u<16;u++) acc[u]=bb;
    for (int i=0;i<64;i++){ float wv = W3[i*20+tid];
      #pragma unroll
      for (int u=0;u<16;u++) acc[u]=fmaf(h2[u][i], wv, acc[u]); }
    #pragma unroll
    for (int u=0;u<16;u++) logits[(r0+u)*20+tid]=acc[u];
  }
}

// ---------------- embed MLP ----------------
__global__ __launch_bounds__(256) void k_embed(const float* __restrict__ x,
    const float* __restrict__ We1, const float* __restrict__ be1,
    const float* __restrict__ We2, const float* __restrict__ be2,
    float* __restrict__ xe){
  __shared__ float xs[16][256];
  __shared__ float h[16][256];
  const int tid = threadIdx.x;
  const int r0 = blockIdx.x * 16;
  for (int u=0;u<16;u++) xs[u][tid] = x[(r0+u)*256 + tid];
  __syncthreads();
  float acc[16];
  { float bb = be1[tid];
    #pragma unroll
    for (int u=0;u<16;u++) acc[u]=bb; }
  for (int i=0;i<256;i++){ float wv = We1[i*256+tid];
    #pragma unroll
    for (int u=0;u<16;u++) acc[u]=fmaf(xs[u][i], wv, acc[u]); }
  #pragma unroll
  for (int u=0;u<16;u++) h[u][tid]=fmaxf(acc[u],0.f);
  __syncthreads();
  { float bb = be2[tid];
    #pragma unroll
    for (int u=0;u<16;u++) acc[u]=bb; }
  for (int i=0;i<256;i++){ float wv = We2[i*256+tid];
    #pragma unroll
    for (int u=0;u<16;u++) acc[u]=fmaf(h[u][i], wv, acc[u]); }
  #pragma unroll
  for (int u=0;u<16;u++) xe[(r0+u)*256+tid]=acc[u];
}

// ---------------- softmax #1 ----------------
__global__ __launch_bounds__(256) void k_sm1(const float* __restrict__ logits, float* __restrict__ colsum0){
  __shared__ float csL[20];
  const int tid = threadIdx.x;
  if (tid < 20) csL[tid]=0.f;
  __syncthreads();
  const int r = blockIdx.x*256 + tid;
  float y[20]; float m = -INFINITY;
  const float4* lp = (const float4*)(logits + r*20);
  #pragma unroll
  for (int q=0;q<5;q++){ float4 f=lp[q]; y[q*4]=f.x; y[q*4+1]=f.y; y[q*4+2]=f.z; y[q*4+3]=f.w; }
  #pragma unroll
  for (int c=0;c<20;c++) m=fmaxf(m,y[c]);
  float s=0.f;
  #pragma unroll
  for (int c=0;c<20;c++){ y[c]=expf(y[c]-m); s+=y[c]; }
  #pragma unroll
  for (int c=0;c<20;c++) atomicAdd(&csL[c], y[c]/s);
  __syncthreads();
  if (tid < 20) atomicAdd(&colsum0[tid], csL[tid]);
}

// ---------------- softmax #2 (column-major out) ----------------
__global__ __launch_bounds__(256) void k_sm2cm(const float* __restrict__ logits, const float* __restrict__ colsum0,
    float* __restrict__ Ucm, float* __restrict__ csG){
  __shared__ float adjv[20]; __shared__ float csL[20];
  const int tid = threadIdx.x;
  if (tid < 20){ adjv[tid] = (0.1f*(colsum0[tid]-307.2f))/307.2f; csL[tid]=0.f; }
  __syncthreads();
  const int r = blockIdx.x*256 + tid;
  float y[20]; float m=-INFINITY;
  const float4* lp = (const float4*)(logits + r*20);
  #pragma unroll
  for (int q=0;q<5;q++){ float4 f=lp[q]; y[q*4]=f.x; y[q*4+1]=f.y; y[q*4+2]=f.z; y[q*4+3]=f.w; }
  #pragma unroll
  for (int c=0;c<20;c++){ y[c]=y[c]-adjv[c]; m=fmaxf(m,y[c]); }
  float s=0.f;
  #pragma unroll
  for (int c=0;c<20;c++){ y[c]=expf(y[c]-m); s+=y[c]; }
  #pragma unroll
  for (int c=0;c<20;c++){ float v=y[c]/s; Ucm[c*6144+r]=v; atomicAdd(&csL[c], v); }
  __syncthreads();
  if (tid < 20) atomicAdd(&csG[tid], csL[tid]);
}

// ---------------- prep: pen transform rows; trow ----------------
__global__ __launch_bounds__(256) void k_prepcm(const float* __restrict__ csG,
    float* __restrict__ Ucm, float* __restrict__ trow){
  __shared__ float pen[20]; __shared__ int flagL;
  const int tid = threadIdx.x;
  if (tid < 20){ float c=csG[tid]; float p=0.f;
    if (c > 20.0f) p = -logf(c/20.0f + 1e-8f);
    if (c > 0.0f && c < 3.0f) p = -0.5f*logf(c/3.0f + 1e-8f);
    pen[tid]=p; }
  __syncthreads();
  if (tid==0){ int f=0; for (int c=0;c<20;c++) if (pen[c]!=0.f) f=1; flagL=f; }
  __syncthreads();
  const int r = blockIdx.x*256 + tid;
  float y[20];
  #pragma unroll
  for (int c=0;c<20;c++) y[c]=Ucm[c*6144+r];
  float ts=0.f;
  if (flagL){
    float m2=-INFINITY;
    #pragma unroll
    for (int c=0;c<20;c++){ y[c]=logf(y[c]+1e-8f)+pen[c]; m2=fmaxf(m2,y[c]); }
    float s2=0.f;
    #pragma unroll
    for (int c=0;c<20;c++){ y[c]=expf(y[c]-m2); s2+=y[c]; }
    #pragma unroll
    for (int c=0;c<20;c++){ float vv=y[c]/s2; Ucm[c*6144+r]=vv; ts+=vv; }
  } else {
    #pragma unroll
    for (int c=0;c<20;c++) ts+=y[c];
  }
  trow[r]=ts;
}

// ---------------- helpers (8-wave block) ----------------
__device__ __forceinline__ void reduce20_8(const float* acc, float* wred, float* out,
                                           int tid, int lane, int wv){
  #pragma unroll
  for (int c=0;c<20;c++){
    float d = acc[c];
    for (int off=32;off>0;off>>=1) d += __shfl_down(d, off);
    if (lane==0) wred[wv*20+c]=d;
  }
  __syncthreads();
  if (tid<20){ float s=0.f; for (int w2=0;w2<8;w2++) s += wred[w2*20+tid]; out[tid]=s; }
  __syncthreads();
}

__device__ __forceinline__ int blockExclScan8(int val, int tid, int lane, int wv,
                                              int* wS, int* totAll){
  __syncthreads();
  int inc = val;
  for (int off=1;off<64;off<<=1){ int nv=__shfl_up(inc,off); if (lane>=off) inc+=nv; }
  if (lane==63) wS[wv]=inc;
  __syncthreads();
  if (tid==0){ int run=0; for (int w2=0;w2<8;w2++){ wS[8+w2]=run; run+=wS[w2]; } *totAll=run; }
  __syncthreads();
  return wS[8+wv] + inc - val;
}

// block radix select, RPT values/thread, 8 lane-salted replicas laid out [bin*8+rep]
// st[0]=prefix, st[1]=count strictly below, st[2]=rank within run, st[3]=run count
__device__ float selectKth12(const float* v, int rank0,
    unsigned* hist, unsigned* st, int* wS, int tid, int lane, int wv){
  __syncthreads();   // protect st from readers of previous select
  if (tid==0){ st[0]=0u; st[1]=0u; st[2]=(unsigned)rank0; st[3]=0u; }
  __syncthreads();
  for (int p=0;p<3;p++){
    const int shift = (p==0)?21:((p==1)?10:0);
    const int bins  = (p==2)?1024:2048;
    { uint4* h4 = (uint4*)hist;
      const int n4 = (bins*8)>>2;
      for (int i=tid;i<n4;i+=MIDT) h4[i] = make_uint4(0u,0u,0u,0u); }
    __syncthreads();
    const unsigned pref = st[0];
    const unsigned rep = (unsigned)(lane & 7);
    unsigned curbin = 0xFFFFFFFFu; unsigned cnt = 0u;
    #pragma unroll
    for (int u=0;u<RPT;u++){
      unsigned key = __float_as_uint(v[u]);
      bool ok;
      if (p==0) ok = true;
      else { int us = (p==1)?21:10; ok = ((key>>us)==(pref>>us)); }
      if (ok){
        unsigned b = (key>>shift)&(unsigned)(bins-1);
        if (b==curbin) cnt++;
        else { if (cnt) atomicAdd(&hist[(curbin<<3)+rep], cnt); curbin=b; cnt=1u; }
      }
    }
    if (cnt) atomicAdd(&hist[(curbin<<3)+rep], cnt);
    __syncthreads();
    const int bpt = bins/MIDT;   // 4 or 2
    unsigned bs[4]; unsigned s=0;
    #pragma unroll
    for (int j=0;j<4;j++) bs[j]=0u;
    for (int j=0;j<bpt;j++){
      const uint4* h4 = (const uint4*)&hist[(unsigned)((tid*bpt+j)<<3)];
      uint4 a=h4[0], b=h4[1];
      unsigned q = a.x+a.y+a.z+a.w+b.x+b.y+b.z+b.w;
      bs[j]=q; s+=q;
    }
    unsigned inc = s;
    for (int off=1;off<64;off<<=1){ unsigned nv=(unsigned)__shfl_up((int)inc,off); if (lane>=off) inc+=nv; }
    if (lane==63) wS[wv]=(int)inc;
    __syncthreads();
    unsigned base=0;
    for (int w2=0;w2<wv;w2++) base += (unsigned)wS[w2];
    unsigned P = base + inc - s;
    const unsigned rank = st[2];
    if (P <= rank && rank < P+s){
      unsigned run = P; int bsel=-1; unsigned hc=0u;
      for (int j=0;j<bpt;j++){ if (run + bs[j] > rank){ bsel = tid*bpt+j; hc=bs[j]; break; } run += bs[j]; }
      st[0] = st[0] | (((unsigned)bsel)<<shift);
      st[1] = st[1] + run;
      st[2] = rank - run;
      st[3] = hc;
    }
    __syncthreads();
  }
  return __uint_as_float(st[0]);
}

// general (reference-faithful) rebalance column step — never taken in this data
// regime; noinline so its register pressure doesn't tax the hot path.
__device__ __attribute__((noinline)) void rebalGeneral(int k, int num, float* Ucm,
    float* G, float* R, const float* wLs, unsigned* hist, unsigned* st, int* wS,
    int* totAllP, int tid, int lane, int wv){
  const int r0 = tid*RPT;
  float u12[RPT];
  const float4* cp = (const float4*)(Ucm + k*6144 + r0);
  #pragma unroll
  for (int q=0;q<RPT/4;q++){ float4 f=cp[q]; u12[q*4]=f.x; u12[q*4+1]=f.y; u12[q*4+2]=f.z; u12[q*4+3]=f.w; }
  int zc=0;
  #pragma unroll
  for (int u=0;u<RPT;u++) zc += (u12[u]==0.0f) ? 1 : 0;
  int zBase = blockExclScan8(zc, tid, lane, wv, wS, totAllP);
  const int totZ = *totAllP;
  bool wk[RPT];
  if (num <= totZ){
    int cnt = zBase;
    #pragma unroll
    for (int u=0;u<RPT;u++){ wk[u]=false; if (u12[u]==0.0f){ if (cnt<num) wk[u]=true; cnt++; } }
  } else {
    float sv12[RPT];
    #pragma unroll
    for (int u=0;u<RPT;u++) sv12[u]=__fmul_rn(u12[u], G[u]);
    float V = selectKth12(sv12, num-1, hist, st, wS, tid, lane, wv);
    unsigned kV = __float_as_uint(V);
    int L = (int)st[1];
    int Rq = num - L;
    int ec=0;
    #pragma unroll
    for (int u=0;u<RPT;u++) ec += (__float_as_uint(sv12[u])==kV) ? 1 : 0;
    int eBase = blockExclScan8(ec, tid, lane, wv, wS, totAllP);
    int cnt = eBase;
    #pragma unroll
    for (int u=0;u<RPT;u++){
      unsigned key = __float_as_uint(sv12[u]); wk[u]=false;
      if (key < kV) wk[u]=true;
      else if (key == kV){ if (cnt < Rq) wk[u]=true; cnt++; }
    }
  }
  #pragma unroll
  for (int u=0;u<RPT;u++){
    if (wk[u]){
      const int r = r0+u;
      float rs=0.f; float xv2[20];
      #pragma unroll
      for (int j=0;j<20;j++){
        float xv = (j==k) ? 1e-8f : __fmul_rn(Ucm[j*6144+r], G[u]);
        xv = __fadd_rn(xv, __fmul_rn(wLs[j], 1e-8f));
        xv2[j]=xv; rs += fabsf(xv);
      }
      float rsm = fmaxf(rs, 1e-12f);
      float nR = 0.f;
      #pragma unroll
      for (int j=0;j<20;j++){
        float nv = __fdiv_rn(xv2[j], rsm);
        Ucm[j*6144+r] = nv; nR += nv;
      }
      G[u]=1.0f; R[u]=nR;
    }
  }
  __syncthreads();
}

// ---------------- sequential middle: constraints + rebalance (512 threads) ----------------
__global__ __launch_bounds__(MIDT,1) void k_midseq(const float* __restrict__ csG,
    const float* __restrict__ trow, float* __restrict__ Ucm, float* __restrict__ Gout){
  __shared__ unsigned hist[2048*8];       // 64 KB, [bin*8+rep]
  __shared__ unsigned st[8];
  __shared__ int wS[16]; __shared__ int totAllS;
  __shared__ unsigned wMin[8];
  __shared__ int wT20[8][20]; __shared__ int wB20[8][20]; __shared__ int totZ20[20];
  __shared__ float wred[160];
  __shared__ float csGs[20], csS[20], wLs[20];
  __shared__ int numL[20], actL[20];
  __shared__ float wsumS; __shared__ int wzeroS; __shared__ int flagS;
  __shared__ int needGenS; __shared__ int anyActS;
  const int tid = threadIdx.x;
  const int lane = tid & 63, wv = tid >> 6;
  const int r0 = tid*RPT;

  float G[RPT], R[RPT];
  { const float4* tp = (const float4*)(trow + r0);
    #pragma unroll
    for (int q=0;q<RPT/4;q++){ float4 f=tp[q]; R[q*4]=f.x; R[q*4+1]=f.y; R[q*4+2]=f.z; R[q*4+3]=f.w; } }
  #pragma unroll
  for (int u=0;u<RPT;u++) G[u]=1.0f;
  if (tid<20) csGs[tid]=csG[tid];
  __syncthreads();
  if (tid==0){ int f=0;
    for (int c=0;c<20;c++){ float cc=csGs[c]; float p=0.f;
      if (cc > 20.0f) p = -logf(cc/20.0f + 1e-8f);
      if (cc > 0.0f && cc < 3.0f) p = -0.5f*logf(cc/3.0f + 1e-8f);
      if (p != 0.f) f=1; }
    flagS=f; }
  __syncthreads();

  // ---- constraints: sequential 20 columns ----
  if (flagS){
    for (int k=0;k<20;k++){
      if (csGs[k] > 30.0f){
        float u12[RPT], sv12[RPT];
        const float4* cp = (const float4*)(Ucm + k*6144 + r0);
        #pragma unroll
        for (int q=0;q<RPT/4;q++){ float4 f=cp[q]; u12[q*4]=f.x; u12[q*4+1]=f.y; u12[q*4+2]=f.z; u12[q*4+3]=f.w; }
        #pragma unroll
        for (int u=0;u<RPT;u++) sv12[u]=__fmul_rn(u12[u], G[u]);
        float vlo = selectKth12(sv12, 4300, hist, st, wS, tid, lane, wv);
        float vhi;
        if (st[2] + 1u < st[3]) vhi = vlo;
        else {
          // min over keys > kV via register/shuffle reduction
          unsigned kV = __float_as_uint(vlo);
          unsigned lm = 0xFFFFFFFFu;
          #pragma unroll
          for (int u=0;u<RPT;u++){ unsigned key=__float_as_uint(sv12[u]); if (key>kV && key<lm) lm=key; }
          for (int off=32;off>0;off>>=1){ unsigned o=(unsigned)__shfl_down((int)lm,off); if (o<lm) lm=o; }
          if (lane==0) wMin[wv]=lm;
          __syncthreads();
          if (tid==0){ unsigned m0=wMin[0];
            for (int w2=1;w2<8;w2++){ unsigned o=wMin[w2]; if (o<m0) m0=o; }
            st[4]=m0; }
          __syncthreads();
          vhi = __uint_as_float(st[4]);
        }
        // jnp.quantile(col,0.7): aq = f32(0.7)*6143 -> exact weights
        float thr = __fadd_rn(__fmul_rn(vlo, 0.89990234375f), __fmul_rn(vhi, 0.10009765625f));
        #pragma unroll
        for (int u=0;u<RPT;u++){
          if (sv12[u] < thr){
            u12[u] = 0.0f;
            float rs  = __fsub_rn(__fmul_rn(R[u], G[u]), sv12[u]);
            float rsm = fmaxf(rs, 1e-12f);
            float uo  = __fdiv_rn(sv12[u], G[u]);   // == original u12 value
            G[u] = __fdiv_rn(G[u], rsm);
            R[u] = __fsub_rn(R[u], uo);
          }
        }
        // coalesced full-column write-back (unchanged entries rewritten identically)
        float4* cpw = (float4*)(Ucm + k*6144 + r0);
        #pragma unroll
        for (int q=0;q<RPT/4;q++){ float4 f; f.x=u12[q*4]; f.y=u12[q*4+1]; f.z=u12[q*4+2]; f.w=u12[q*4+3]; cpw[q]=f; }
      }
    }
  }
  __syncthreads();

  // ---- hard rebalance: 5 iterations ----
  for (int it=0; it<5; it++){
    float acc[20];
    int zb[RPT];
    #pragma unroll
    for (int u=0;u<RPT;u++) zb[u]=0;
    for (int c=0;c<20;c++){
      const float4* cp = (const float4*)(Ucm + c*6144 + r0);
      float vv[RPT];
      #pragma unroll
      for (int q=0;q<RPT/4;q++){ float4 f=cp[q]; vv[q*4]=f.x; vv[q*4+1]=f.y; vv[q*4+2]=f.z; vv[q*4+3]=f.w; }
      float d=0.f;
      #pragma unroll
      for (int u=0;u<RPT;u++){
        if (vv[u]==0.0f) zb[u] |= (1<<c);
        d += __fmul_rn(vv[u], G[u]);
      }
      acc[c]=d;
    }
    reduce20_8(acc, wred, csS, tid, lane, wv);
    if (tid==0){ float s=0.f; for (int c=0;c<20;c++) s += fmaxf(20.0f-csS[c],0.f);
      wzeroS = (s==0.0f) ? 1 : 0; wsumS = s + 1e-8f; }
    __syncthreads();
    if (tid<20){
      float csf = csS[tid];
      actL[tid] = (csf > 20.0f) ? 1 : 0;
      int num = (int)ceilf(csf - 20.0f) + 5; if (num > 6144) num = 6144;
      numL[tid] = num;
      wLs[tid] = fmaxf(20.0f-csf,0.f) / wsumS;
    }
    __syncthreads();
    // batched 20-column exclusive scan of per-thread zero counts
    int exc[20];
    #pragma unroll
    for (int c=0;c<20;c++){
      int z=0;
      #pragma unroll
      for (int u=0;u<RPT;u++) z += (zb[u]>>c)&1;
      int inc = z;
      for (int off=1;off<64;off<<=1){ int nv=__shfl_up(inc,off); if (lane>=off) inc+=nv; }
      if (lane==63) wT20[wv][c]=inc;
      exc[c]=inc-z;
    }
    __syncthreads();
    if (tid<20){
      int run=0;
      for (int w2=0;w2<8;w2++){ wB20[w2][tid]=run; run+=wT20[w2][tid]; }
      totZ20[tid]=run;
    }
    __syncthreads();
    if (tid==0){
      int ng=0, aa=0;
      for (int c=0;c<20;c++) if (actL[c]){ aa=1; if (numL[c] > totZ20[c]) ng=1; }
      if (aa && !wzeroS) ng=1;
      needGenS=ng; anyActS=aa;
    }
    __syncthreads();
    if (!anyActS) continue;
    if (!needGenS){
      // fast path: all 20 columns in parallel; weak = first num exact-zero rows by index
      #pragma unroll
      for (int c=0;c<20;c++){
        if (actL[c]){
          int rank = wB20[wv][c] + exc[c];
          const int num = numL[c];
          #pragma unroll
          for (int u=0;u<RPT;u++){
            if ((zb[u]>>c)&1){
              if (rank < num){
                float Gold = G[u];
                float t   = __fadd_rn(__fmul_rn(R[u], Gold), 1e-8f);
                float rsm = fmaxf(t, 1e-12f);
                float un  = __fdiv_rn(1e-8f, Gold);
                Ucm[c*6144+r0+u] = un;
                G[u] = __fdiv_rn(Gold, rsm);
                R[u] = __fadd_rn(R[u], un);
              }
              rank++;
            }
          }
        }
      }
      __syncthreads();
    } else {
      for (int k=0;k<20;k++){
        if (actL[k]) rebalGeneral(k, numL[k], Ucm, G, R, wLs, hist, st, wS, &totAllS, tid, lane, wv);
      }
    }
  }

  // ---- emit per-row scale ----
  { float4* gp = (float4*)(Gout + r0);
    #pragma unroll
    for (int q=0;q<RPT/4;q++){ float4 f; f.x=G[q*4]; f.y=G[q*4+1]; f.z=G[q*4+2]; f.w=G[q*4+3]; gp[q]=f; } }
}

// ---------------- final: materialize S (outS + SW), entropy, cs_final, x_pooled ----------------
__global__ __launch_bounds__(256) void k_final(const float* __restrict__ Ucm, const float* __restrict__ Gout,
    const float* __restrict__ xe, float* __restrict__ outXP, float* __restrict__ outS,
    float* __restrict__ SW, float* __restrict__ csfin, double* __restrict__ entAcc){
  __shared__ float Sblk[256][21];
  __shared__ float csL[20];
  __shared__ double entL[4];
  const int tid = threadIdx.x;
  const int r0 = blockIdx.x * 256;
  const int lane = tid & 63, wvq = tid >> 6;
  if (tid < 20) csL[tid]=0.f;
  __syncthreads();
  {
    const int r = r0 + tid;
    const float Gr = Gout[r];
    float sv[20]; float ent=0.f;
    #pragma unroll
    for (int c=0;c<20;c++) sv[c]=__fmul_rn(Ucm[c*6144+r], Gr);
    float4* so = (float4*)(outS + r*20);
    float4* sw = (float4*)(SW + r*20);
    #pragma unroll
    for (int q=0;q<5;q++){ float4 f; f.x=sv[q*4]; f.y=sv[q*4+1]; f.z=sv[q*4+2]; f.w=sv[q*4+3]; so[q]=f; sw[q]=f; }
    #pragma unroll
    for (int c=0;c<20;c++){ Sblk[tid][c]=sv[c]; ent += sv[c]*logf(sv[c]+1e-08f); }
    #pragma unroll
    for (int c=0;c<20;c++) atomicAdd(&csL[c], sv[c]);
    double ed = (double)ent;
    for (int off=32;off>0;off>>=1) ed += __shfl_down(ed, off);
    if (lane==0) entL[wvq]=ed;
  }
  __syncthreads();
  if (tid==0) atomicAdd(entAcc, entL[0]+entL[1]+entL[2]+entL[3]);
  if (tid<20) atomicAdd(&csfin[tid], csL[tid]);
  float acc[20];
  #pragma unroll
  for (int c=0;c<20;c++) acc[c]=0.f;
  for (int i=0;i<256;i++){
    float xv = xe[(r0+i)*256 + tid];
    #pragma unroll
    for (int c=0;c<20;c++) acc[c]=fmaf(Sblk[i][c], xv, acc[c]);
  }
  #pragma unroll
  for (int c=0;c<20;c++) atomicAdd(&outXP[c*256+tid], acc[c]);
}

// ---------------- bitmap build (dedup only) ----------------
__global__ __launch_bounds__(256) void k_bitmap(const int* __restrict__ ei,
    unsigned int* __restrict__ bitmap){
  const int e = blockIdx.x*256 + threadIdx.x;
  const int i = ei[e], j = ei[NE+e];
  unsigned bit = (unsigned)i*6144u + (unsigned)j;
  atomicOr(&bitmap[bit >> 5], 1u << (bit & 31u));
}

// ---------------- bitmap scan: T = adj@S rows (no atomics) + dedup'd edge loss ----------------
__global__ __launch_bounds__(256) void k_adjT(const unsigned* __restrict__ bitmap,
    const float* __restrict__ SW, float* __restrict__ T, double* __restrict__ edgeAcc){
  __shared__ double wsum[4];
  const int tid = threadIdx.x;
  const int lane = tid & 63, wvq = tid >> 6;
  const int rbase = blockIdx.x*64 + wvq*16;   // 96 blocks x 4 waves x 16 rows
  float eacc = 0.f;
  for (int rr=0; rr<16; rr++){
    const int i = rbase + rr;
    float Si[20];
    { const float4* sp = (const float4*)(SW + i*20);
      #pragma unroll
      for (int q=0;q<5;q++){ float4 f=sp[q]; Si[q*4]=f.x; Si[q*4+1]=f.y; Si[q*4+2]=f.z; Si[q*4+3]=f.w; } }
    float Tp[20];
    #pragma unroll
    for (int c=0;c<20;c++) Tp[c]=0.f;
    #pragma unroll
    for (int w=0; w<3; w++){
      const int wq = lane + w*64;             // word index within row, 0..191
      unsigned word = bitmap[i*192 + wq];
      while (word){
        int b = __ffs((int)word) - 1; word &= (word-1u);
        int j = wq*32 + b;
        const float4* sj = (const float4*)(SW + j*20);
        float p = 0.f;
        #pragma unroll
        for (int q=0;q<5;q++){
          float4 f = sj[q];
          Tp[q*4]+=f.x; Tp[q*4+1]+=f.y; Tp[q*4+2]+=f.z; Tp[q*4+3]+=f.w;
          p = fmaf(Si[q*4],f.x, fmaf(Si[q*4+1],f.y, fmaf(Si[q*4+2],f.z, fmaf(Si[q*4+3],f.w, p))));
        }
        float pcl = fminf(fmaxf(p,0.f),1.f);
        float lg  = fmaxf(logf(pcl),   -100.f);
        float l1  = fmaxf(log1pf(-pcl),-100.f);
        eacc += (lg - l1);
      }
    }
    // wave-reduce Tp and store row
    float tr[20];
    #pragma unroll
    for (int c=0;c<20;c++){
      float t = Tp[c];
      for (int off=32;off>0;off>>=1) t += __shfl_down(t, off);
      tr[c]=t;
    }
    if (lane==0){
      float4* tw = (float4*)(T + i*20);
      #pragma unroll
      for (int q=0;q<5;q++){ float4 f; f.x=tr[q*4]; f.y=tr[q*4+1]; f.z=tr[q*4+2]; f.w=tr[q*4+3]; tw[q]=f; }
    }
  }
  double cd = (double)eacc;
  for (int off=32;off>0;off>>=1) cd += __shfl_down(cd, off);
  if (lane==0) wsum[wvq]=cd;
  __syncthreads();
  if (tid==0) atomicAdd(edgeAcc, wsum[0]+wsum[1]+wsum[2]+wsum[3]);
}

// ---------------- adj_pooled = S.T @ T ----------------
__global__ __launch_bounds__(400) void k_adjpool(const float* __restrict__ SW, const float* __restrict__ T,
    float* __restrict__ outAdj){
  const int tid = threadIdx.x;
  const int c = tid/20, d = tid%20;
  const int r0 = blockIdx.x*256;
  float acc=0.f;
  for (int i=0;i<256;i++) acc = fmaf(SW[(r0+i)*20+c], T[(r0+i)*20+d], acc);
  atomicAdd(&outAdj[c*20+d], acc);
}

// ---------------- all-pair sum of clamped log1p(-p) ----------------
__global__ __launch_bounds__(256) void k_link(const float* __restrict__ SW, double* __restrict__ acc){
  __shared__ float Si[256][21];
  __shared__ float Sj[256][21];
  __shared__ double wsum[4];
  const int tid = threadIdx.x;
  const int ib = blockIdx.x*256, jb = blockIdx.y*256;
  const int lane = tid & 63, wvq = tid >> 6;
  for (int idx=tid; idx<5120; idx+=256){ int r=idx/20, c=idx%20; Si[r][c]=SW[(ib+r)*20+c]; }
  for (int idx=tid; idx<5120; idx+=256){ int r=idx/20, c=idx%20; Sj[r][c]=SW[(jb+r)*20+c]; }
  __syncthreads();
  float rA[20];
  #pragma unroll
  for (int c=0;c<20;c++) rA[c]=Si[tid][c];
  float af = 0.f;
  for (int jj=0;jj<256;jj++){
    float p=0.f;
    #pragma unroll
    for (int c=0;c<20;c++) p = fmaf(rA[c], Sj[jj][c], p);
    float pcl = fminf(fmaxf(p,0.f),1.f);
    af += fmaxf(log1pf(-pcl), -100.f);
  }
  double cd = (double)af;
  for (int off=32;off>0;off>>=1) cd += __shfl_down(cd, off);
  if (lane==0) wsum[wvq]=cd;
  __syncthreads();
  if (tid==0) atomicAdd(acc, wsum[0]+wsum[1]+wsum[2]+wsum[3]);
}

// ---------------- aux scalar ----------------
__global__ void k_aux(const double* __restrict__ dAcc, const float* __restrict__ csfin, float* __restrict__ outAux){
  const double nsq = 6144.0*6144.0;
  float link = (float)(-(dAcc[0]+dAcc[1])/nsq);
  float ent  = (float)(-(dAcc[2]/6144.0));
  float s=0.f;
  for (int c=0;c<20;c++) s += fabsf(csfin[c]-307.2f);
  float bal = (s/20.0f)/307.2f;
  outAux[0] = link + 0.1f*ent + 0.5f*bal;
}

extern "C" void kernel_launch(void* const* d_in, const int* in_sizes, int n_in,
                              void* d_out, int out_size, void* d_ws, size_t ws_size,
                              hipStream_t stream) {
  const float* x   = (const float*)d_in[0];
  const int*   ei  = (const int*)d_in[1];
  // d_in[2] = lv_group_ids: dead (LV table is never 0 -> mask is identity)
  const float* W1  = (const float*)d_in[3];
  const float* b1  = (const float*)d_in[4];
  const float* W2  = (const float*)d_in[5];
  const float* b2  = (const float*)d_in[6];
  const float* W3  = (const float*)d_in[7];
  const float* b3  = (const float*)d_in[8];
  const float* We1 = (const float*)d_in[9];
  const float* be1 = (const float*)d_in[10];
  const float* We2 = (const float*)d_in[11];
  const float* be2 = (const float*)d_in[12];

  char* ws = (char*)d_ws;
  float* T        = (float*)(ws + OFF_T);
  unsigned int* bitmap = (unsigned int*)(ws + OFF_BITMAP);
  float* colsum0  = (float*)(ws + OFF_COLSUM0);
  float* csG      = (float*)(ws + OFF_CSG);
  float* csfin    = (float*)(ws + OFF_CSFIN);
  double* dAcc    = (double*)(ws + OFF_DACC);
  float* logits   = (float*)(ws + OFF_LOGITS);
  float* Ucm      = (float*)(ws + OFF_UCM);
  float* SW       = (float*)(ws + OFF_SW);
  float* xe       = (float*)(ws + OFF_XE);
  float* trow     = (float*)(ws + OFF_TROW);
  float* Gout     = (float*)(ws + OFF_GOUT);

  float* out   = (float*)d_out;
  float* outXP = out;            // 20*256
  float* outAdj= out + 5120;     // 20*20
  float* outS  = out + 5520;     // 6144*20
  float* outAux= out + 128400;   // 1

  hipMemsetAsync(d_ws, 0, (size_t)ZERO_BYTES, stream);
  hipMemsetAsync(d_out, 0, (size_t)out_size*sizeof(float), stream);

  k_mlp<<<384, 128, 0, stream>>>(x, W1,b1, W2,b2, W3,b3, logits);
  k_embed<<<384, 256, 0, stream>>>(x, We1,be1, We2,be2, xe);
  k_sm1<<<24, 256, 0, stream>>>(logits, colsum0);
  k_sm2cm<<<24, 256, 0, stream>>>(logits, colsum0, Ucm, csG);
  k_prepcm<<<24, 256, 0, stream>>>(csG, Ucm, trow);
  k_midseq<<<1, MIDT, 0, stream>>>(csG, trow, Ucm, Gout);
  k_bitmap<<<384, 256, 0, stream>>>(ei, bitmap);
  k_final<<<24, 256, 0, stream>>>(Ucm, Gout, xe, outXP, outS, SW, csfin, &dAcc[2]);
  k_adjT<<<96, 256, 0, stream>>>(bitmap, SW, T, &dAcc[1]);
  k_adjpool<<<24, 400, 0, stream>>>(SW, T, outAdj);
  k_link<<<dim3(24,24), 256, 0, stream>>>(SW, &dAcc[0]);
  k_aux<<<1, 1, 0, stream>>>(dAcc, csfin, outAux);
}

// Round 8
// 1546.320 us; speedup vs baseline: 1.0028x; 1.0028x over previous
//
#include <hip/hip_runtime.h>
#include <math.h>

#define N_NODES 6144
#define KCL 20
#define NE 98304
#define RPT 24      // rows per thread in the sequential kernel (256 thr)

// ---------------- workspace layout (bytes) ----------------
#define OFF_T        0ull          // 122880 f32 (zeroed)
#define OFF_BITMAP   491520ull     // 4718592 B bitmap (zeroed)
#define OFF_COLSUM0  5210112ull    // 20 f32 (zeroed)
#define OFF_CSG      5210192ull    // 20 f32 (zeroed)
#define OFF_CSFIN    5210272ull    // 20 f32 (zeroed)
#define OFF_DACC     5210368ull    // 4 doubles (zeroed)
#define ZERO_BYTES   5210400ull
#define OFF_LOGITS   5210624ull    // 6144*20 f32 row-major
#define OFF_UCM      5702144ull    // 6144*20 f32 column-major (unscaled S)
#define OFF_SW       6193664ull    // 6144*20 f32 row-major (final S)
#define OFF_XE       6685184ull    // 6144*256 f32
#define OFF_TROW     12976640ull   // 6144 f32
#define OFF_GOUT     13001216ull   // 6144 f32

// ---------------- MLP: logits ----------------
__global__ __launch_bounds__(128) void k_mlp(const float* __restrict__ x,
    const float* __restrict__ W1, const float* __restrict__ b1,
    const float* __restrict__ W2, const float* __restrict__ b2,
    const float* __restrict__ W3, const float* __restrict__ b3,
    float* __restrict__ logits){
  __shared__ float xs[16][256];
  __shared__ float h1[16][128];
  __shared__ float h2[16][64];
  const int tid = threadIdx.x;
  const int r0 = blockIdx.x * 16;
  for (int idx = tid; idx < 16*256; idx += 128){ int u = idx >> 8, i = idx & 255; xs[u][i] = x[(r0+u)*256 + i]; }
  __syncthreads();
  {
    float acc[16]; float bb = b1[tid];
    #pragma unroll
    for (int u=0;u<16;u++) acc[u]=bb;
    for (int i=0;i<256;i++){ float wv = W1[i*128+tid];
      #pragma unroll
      for (int u=0;u<16;u++) acc[u]=fmaf(xs[u][i], wv, acc[u]); }
    #pragma unroll
    for (int u=0;u<16;u++) h1[u][tid]=fmaxf(acc[u],0.f);
  }
  __syncthreads();
  if (tid < 64){
    float acc[16]; float bb = b2[tid];
    #pragma unroll
    for (int u=0;u<16;u++) acc[u]=bb;
    for (int i=0;i<128;i++){ float wv = W2[i*64+tid];
      #pragma unroll
      for (int u=0;u<16;u++) acc[u]=fmaf(h1[u][i], wv, acc[u]); }
    #pragma unroll
    for (int u=0;u<16;u++) h2[u][tid]=fmaxf(acc[u],0.f);
  }
  __syncthreads();
  if (tid < 20){
    float acc[16]; float bb = b3[tid];
    #pragma unroll
    for (int u=0;u<16;u++) acc[u]=bb;
    for (int i=0;i<64;i++){ float wv = W3[i*20+tid];
      #pragma unroll
      for (int u=0;u<16;u++) acc[u]=fmaf(h2[u][i], wv, acc[u]); }
    #pragma unroll
    for (int u=0;u<16;u++) logits[(r0+u)*20+tid]=acc[u];
  }
}

// ---------------- embed MLP ----------------
__global__ __launch_bounds__(256) void k_embed(const float* __restrict__ x,
    const float* __restrict__ We1, const float* __restrict__ be1,
    const float* __restrict__ We2, const float* __restrict__ be2,
    float* __restrict__ xe){
  __shared__ float xs[16][256];
  __shared__ float h[16][256];
  const int tid = threadIdx.x;
  const int r0 = blockIdx.x * 16;
  for (int u=0;u<16;u++) xs[u][tid] = x[(r0+u)*256 + tid];
  __syncthreads();
  float acc[16];
  { float bb = be1[tid];
    #pragma unroll
    for (int u=0;u<16;u++) acc[u]=bb; }
  for (int i=0;i<256;i++){ float wv = We1[i*256+tid];
    #pragma unroll
    for (int u=0;u<16;u++) acc[u]=fmaf(xs[u][i], wv, acc[u]); }
  #pragma unroll
  for (int u=0;u<16;u++) h[u][tid]=fmaxf(acc[u],0.f);
  __syncthreads();
  { float bb = be2[tid];
    #pragma unroll
    for (int u=0;u<16;u++) acc[u]=bb; }
  for (int i=0;i<256;i++){ float wv = We2[i*256+tid];
    #pragma unroll
    for (int u=0;u<16;u++) acc[u]=fmaf(h[u][i], wv, acc[u]); }
  #pragma unroll
  for (int u=0;u<16;u++) xe[(r0+u)*256+tid]=acc[u];
}

// ---------------- softmax #1 ----------------
__global__ __launch_bounds__(256) void k_sm1(const float* __restrict__ logits, float* __restrict__ colsum0){
  __shared__ float csL[20];
  const int tid = threadIdx.x;
  if (tid < 20) csL[tid]=0.f;
  __syncthreads();
  const int r = blockIdx.x*256 + tid;
  float y[20]; float m = -INFINITY;
  const float4* lp = (const float4*)(logits + r*20);
  #pragma unroll
  for (int q=0;q<5;q++){ float4 f=lp[q]; y[q*4]=f.x; y[q*4+1]=f.y; y[q*4+2]=f.z; y[q*4+3]=f.w; }
  #pragma unroll
  for (int c=0;c<20;c++) m=fmaxf(m,y[c]);
  float s=0.f;
  #pragma unroll
  for (int c=0;c<20;c++){ y[c]=expf(y[c]-m); s+=y[c]; }
  #pragma unroll
  for (int c=0;c<20;c++) atomicAdd(&csL[c], y[c]/s);
  __syncthreads();
  if (tid < 20) atomicAdd(&colsum0[tid], csL[tid]);
}

// ---------------- softmax #2 (column-major out) ----------------
__global__ __launch_bounds__(256) void k_sm2cm(const float* __restrict__ logits, const float* __restrict__ colsum0,
    float* __restrict__ Ucm, float* __restrict__ csG){
  __shared__ float adjv[20]; __shared__ float csL[20];
  const int tid = threadIdx.x;
  if (tid < 20){ adjv[tid] = (0.1f*(colsum0[tid]-307.2f))/307.2f; csL[tid]=0.f; }
  __syncthreads();
  const int r = blockIdx.x*256 + tid;
  float y[20]; float m=-INFINITY;
  const float4* lp = (const float4*)(logits + r*20);
  #pragma unroll
  for (int q=0;q<5;q++){ float4 f=lp[q]; y[q*4]=f.x; y[q*4+1]=f.y; y[q*4+2]=f.z; y[q*4+3]=f.w; }
  #pragma unroll
  for (int c=0;c<20;c++){ y[c]=y[c]-adjv[c]; m=fmaxf(m,y[c]); }
  float s=0.f;
  #pragma unroll
  for (int c=0;c<20;c++){ y[c]=expf(y[c]-m); s+=y[c]; }
  #pragma unroll
  for (int c=0;c<20;c++){ float v=y[c]/s; Ucm[c*6144+r]=v; atomicAdd(&csL[c], v); }
  __syncthreads();
  if (tid < 20) atomicAdd(&csG[tid], csL[tid]);
}

// ---------------- prep: pen transform rows; trow ----------------
__global__ __launch_bounds__(256) void k_prepcm(const float* __restrict__ csG,
    float* __restrict__ Ucm, float* __restrict__ trow){
  __shared__ float pen[20]; __shared__ int flagL;
  const int tid = threadIdx.x;
  if (tid < 20){ float c=csG[tid]; float p=0.f;
    if (c > 20.0f) p = -logf(c/20.0f + 1e-8f);
    if (c > 0.0f && c < 3.0f) p = -0.5f*logf(c/3.0f + 1e-8f);
    pen[tid]=p; }
  __syncthreads();
  if (tid==0){ int f=0; for (int c=0;c<20;c++) if (pen[c]!=0.f) f=1; flagL=f; }
  __syncthreads();
  const int r = blockIdx.x*256 + tid;
  float y[20];
  #pragma unroll
  for (int c=0;c<20;c++) y[c]=Ucm[c*6144+r];
  float ts=0.f;
  if (flagL){
    float m2=-INFINITY;
    #pragma unroll
    for (int c=0;c<20;c++){ y[c]=logf(y[c]+1e-8f)+pen[c]; m2=fmaxf(m2,y[c]); }
    float s2=0.f;
    #pragma unroll
    for (int c=0;c<20;c++){ y[c]=expf(y[c]-m2); s2+=y[c]; }
    #pragma unroll
    for (int c=0;c<20;c++){ float vv=y[c]/s2; Ucm[c*6144+r]=vv; ts+=vv; }
  } else {
    #pragma unroll
    for (int c=0;c<20;c++) ts+=y[c];
  }
  trow[r]=ts;
}

// ================= sequential middle machinery (256 thr, 4 waves) =================
// hist: 4 replica planes of 2056 words each; word(bin,rep) = rep*2056 + (bin ^ ((bin>>5)&31))
#define HPLANE 2056
#define HWORDS (4*HPLANE)

__device__ __forceinline__ int blockExclScan4(int val, int tid, int lane, int wv,
                                              int* wS, int* totAll){
  __syncthreads();
  int inc = val;
  for (int off=1;off<64;off<<=1){ int nv=__shfl_up(inc,off); if (lane>=off) inc+=nv; }
  if (lane==63) wS[wv]=inc;
  __syncthreads();
  if (tid==0){ int run=0; for (int w2=0;w2<4;w2++){ wS[4+w2]=run; run+=wS[w2]; } *totAll=run; }
  __syncthreads();
  return wS[4+wv] + inc - val;
}

template<int SHIFT, int US, int BINS, bool PREFIX>
__device__ __forceinline__ void atomicPass(const float* u, const float* G,
    unsigned* hist, unsigned* stp, int lane){
  const unsigned pref = PREFIX ? stp[0] : 0u;
  const unsigned rep = (unsigned)(lane & 3) * HPLANE;
  unsigned curbin=0xFFFFFFFFu, cnt=0u;
  #pragma unroll
  for (int i=0;i<RPT;i++){
    unsigned key = __float_as_uint(__fmul_rn(u[i], G[i]));
    bool ok = (!PREFIX) || ((key>>US)==(pref>>US));
    if (ok){
      unsigned b = (key>>SHIFT)&(unsigned)(BINS-1);
      if (b==curbin) cnt++;
      else { if (cnt) atomicAdd(&hist[rep + (curbin ^ ((curbin>>5)&31u))], cnt); curbin=b; cnt=1u; }
    }
  }
  if (cnt) atomicAdd(&hist[rep + (curbin ^ ((curbin>>5)&31u))], cnt);
}

// wave0-only resolve: sum replicas, zero-after-read, scan, update st; p3 also derives vhi.
template<int SHIFT, int BINS, bool DOVHI>
__device__ __forceinline__ void resolvePass(unsigned* hist, unsigned* stp, int lane, int wv){
  if (wv != 0) return;
  const int A = BINS >> 5;                 // active lanes (32 bins each)
  const bool act = lane < A;
  const int bbase = lane*32;
  unsigned cnt[32]; int tot=0;
  #pragma unroll
  for (int j=0;j<32;j++){
    unsigned s=0u;
    if (act){
      int b = bbase + j;
      unsigned w = (unsigned)(b ^ ((b>>5)&31));
      s = hist[w] + hist[HPLANE+w] + hist[2*HPLANE+w] + hist[3*HPLANE+w];
      hist[w]=0u; hist[HPLANE+w]=0u; hist[2*HPLANE+w]=0u; hist[3*HPLANE+w]=0u;
    }
    cnt[j]=s; tot += (int)s;
  }
  int inc = tot;
  for (int off=1;off<64;off<<=1){ int nv=__shfl_up(inc,off); if (lane>=off) inc+=nv; }
  const int excl = inc - tot;
  const unsigned rank = stp[2];
  const bool own = act && ((int)rank >= excl) && ((int)rank < excl + tot);
  int run = excl, jsel = -1; unsigned hc = 0u;
  #pragma unroll
  for (int j=0;j<32;j++){
    if (own && jsel < 0){
      if (run + (int)cnt[j] > (int)rank){ jsel = j; hc = cnt[j]; }
      else run += (int)cnt[j];
    }
  }
  unsigned relnew = rank - (unsigned)run;
  if (own){
    stp[0] = stp[0] | (((unsigned)(bbase + jsel)) << SHIFT);
    stp[1] = stp[1] + (unsigned)run;
    stp[2] = relnew;
    stp[3] = hc;
  }
  if (DOVHI){
    unsigned long long obal = __ballot(own);
    int ol = (int)__ffsll((unsigned long long)obal) - 1;
    int vbin = __shfl(own ? (bbase + jsel) : 0, ol);
    int cand = 0x7FFFFFFF;
    if (act){
      #pragma unroll
      for (int j=0;j<32;j++){ int b=bbase+j; if (b>vbin && cnt[j]>0u && b<cand) cand=b; }
    }
    for (int off=32;off>0;off>>=1){ int o=__shfl_xor(cand,off); if (o<cand) cand=o; }
    if (lane == ol){
      unsigned vloB = stp[0];
      bool tie = (relnew + 1u < hc);
      unsigned vhB = tie ? vloB
                   : ((cand != 0x7FFFFFFF) ? ((vloB & ~1023u) | (unsigned)cand) : 0xFFFFFFFFu);
      stp[4] = vhB;
    }
  }
}

// full select: rank-th smallest of {u[i]*G[i]} over the block; 6 barriers.
// post: stp[0]=vlo bits, stp[1]=count strictly below run, stp[2]=rank in run,
//       stp[3]=run count, stp[4]=vhi bits or 0xFFFFFFFF (fallback needed)
__device__ void selectK(const float* u, const float* G, int rank0,
    unsigned* hist, unsigned* stp, int tid, int lane, int wv){
  if (tid==0){ stp[0]=0u; stp[1]=0u; stp[2]=(unsigned)rank0; stp[3]=0u; stp[4]=0u; }
  atomicPass<21,21,2048,false>(u,G,hist,stp,lane);
  __syncthreads();
  resolvePass<21,2048,false>(hist,stp,lane,wv);
  __syncthreads();
  atomicPass<10,21,2048,true>(u,G,hist,stp,lane);
  __syncthreads();
  resolvePass<10,2048,false>(hist,stp,lane,wv);
  __syncthreads();
  atomicPass<0,10,1024,true>(u,G,hist,stp,lane);
  __syncthreads();
  resolvePass<0,1024,true>(hist,stp,lane,wv);
  __syncthreads();
}

__device__ __forceinline__ void loadcol24(float* v, const float* __restrict__ Ucm, int c, int r0){
  const float4* cp = (const float4*)(Ucm + c*6144 + r0);
  #pragma unroll
  for (int q=0;q<RPT/4;q++){ float4 f=cp[q]; v[q*4]=f.x; v[q*4+1]=f.y; v[q*4+2]=f.z; v[q*4+3]=f.w; }
}
__device__ __forceinline__ void storecol24(const float* v, float* __restrict__ Ucm, int c, int r0){
  float4* cp = (float4*)(Ucm + c*6144 + r0);
  #pragma unroll
  for (int q=0;q<RPT/4;q++){ float4 f; f.x=v[q*4]; f.y=v[q*4+1]; f.z=v[q*4+2]; f.w=v[q*4+3]; cp[q]=f; }
}

// general (reference-faithful) rebalance column step — not taken in this data regime
__device__ __attribute__((noinline)) void rebalGeneral(int k, int num, float* Ucm,
    float* G, float* R, const float* wLs, unsigned* hist, unsigned (*stb)[8], int par,
    int* wS, int* totAllP, int tid, int lane, int wv){
  const int r0 = tid*RPT;
  float u24[RPT];
  loadcol24(u24, Ucm, k, r0);
  int zc=0;
  #pragma unroll
  for (int u=0;u<RPT;u++) zc += (u24[u]==0.0f) ? 1 : 0;
  int zBase = blockExclScan4(zc, tid, lane, wv, wS, totAllP);
  const int totZ = *totAllP;
  bool wk[RPT];
  if (num <= totZ){
    int cnt = zBase;
    #pragma unroll
    for (int u=0;u<RPT;u++){ wk[u]=false; if (u24[u]==0.0f){ if (cnt<num) wk[u]=true; cnt++; } }
  } else {
    unsigned* stp = stb[par];
    selectK(u24, G, num-1, hist, stp, tid, lane, wv);
    unsigned kV = stp[0];
    int L = (int)stp[1];
    int Rq = num - L;
    int ec=0;
    #pragma unroll
    for (int u=0;u<RPT;u++) ec += (__float_as_uint(__fmul_rn(u24[u],G[u]))==kV) ? 1 : 0;
    int eBase = blockExclScan4(ec, tid, lane, wv, wS, totAllP);
    int cnt = eBase;
    #pragma unroll
    for (int u=0;u<RPT;u++){
      unsigned key = __float_as_uint(__fmul_rn(u24[u],G[u])); wk[u]=false;
      if (key < kV) wk[u]=true;
      else if (key == kV){ if (cnt < Rq) wk[u]=true; cnt++; }
    }
  }
  #pragma unroll
  for (int u=0;u<RPT;u++){
    if (wk[u]){
      const int r = r0+u;
      float rs=0.f; float xv2[20];
      #pragma unroll
      for (int j=0;j<20;j++){
        float xv = (j==k) ? 1e-8f : __fmul_rn(Ucm[j*6144+r], G[u]);
        xv = __fadd_rn(xv, __fmul_rn(wLs[j], 1e-8f));
        xv2[j]=xv; rs += fabsf(xv);
      }
      float rsm = fmaxf(rs, 1e-12f);
      float nR = 0.f;
      #pragma unroll
      for (int j=0;j<20;j++){
        float nv = __fdiv_rn(xv2[j], rsm);
        Ucm[j*6144+r] = nv; nR += nv;
      }
      G[u]=1.0f; R[u]=nR;
    }
  }
  __syncthreads();
}

// ---------------- sequential middle: constraints + rebalance (256 threads) ----------------
__global__ __launch_bounds__(256,1) void k_midseq(const float* __restrict__ csG,
    const float* __restrict__ trow, float* __restrict__ Ucm, float* __restrict__ Gout){
  __shared__ unsigned hist[HWORDS];        // ~33 KB
  __shared__ unsigned stb[2][8];
  __shared__ unsigned wMinB[2][4];
  __shared__ float accW[2][4][20];
  __shared__ int   zcW[2][4][20];
  __shared__ float csGs[20];
  __shared__ float wLs[20];
  __shared__ int wS[8]; __shared__ int totAllS;
  const int tid = threadIdx.x;
  const int lane = tid & 63, wv = tid >> 6;
  const int r0 = tid*RPT;

  // entry: zero hist, stage csG, load G/R
  for (int i=tid;i<HWORDS;i+=256) hist[i]=0u;
  if (tid<20) csGs[tid]=csG[tid];
  float G[RPT], R[RPT];
  { const float4* tp = (const float4*)(trow + r0);
    #pragma unroll
    for (int q=0;q<RPT/4;q++){ float4 f=tp[q]; R[q*4]=f.x; R[q*4+1]=f.y; R[q*4+2]=f.z; R[q*4+3]=f.w; } }
  #pragma unroll
  for (int u=0;u<RPT;u++) G[u]=1.0f;
  __syncthreads();
  // redundant pen/flag
  int flag=0;
  for (int c=0;c<20;c++){ float cc=csGs[c]; float p=0.f;
    if (cc > 20.0f) p = -logf(cc/20.0f + 1e-8f);
    if (cc > 0.0f && cc < 3.0f) p = -0.5f*logf(cc/3.0f + 1e-8f);
    if (p != 0.f) flag=1; }

  int selCnt = 0;

  // ---- constraints: sequential 20 columns, prefetched ----
  if (flag){
    float uC[RPT], uN[RPT];
    loadcol24(uC, Ucm, 0, r0);
    #pragma unroll 1
    for (int k=0;k<20;k++){
      if (k<19) loadcol24(uN, Ucm, k+1, r0);
      if (csGs[k] > 30.0f){
        const int par = selCnt & 1; selCnt++;
        unsigned* stp = stb[par];
        selectK(uC, G, 4300, hist, stp, tid, lane, wv);
        unsigned vloB = stp[0];
        unsigned vhB  = stp[4];
        if (vhB == 0xFFFFFFFFu){
          // fallback: min over values strictly greater than vlo
          unsigned lm = 0xFFFFFFFFu;
          #pragma unroll
          for (int u=0;u<RPT;u++){ unsigned key=__float_as_uint(__fmul_rn(uC[u],G[u])); if (key>vloB && key<lm) lm=key; }
          for (int off=32;off>0;off>>=1){ unsigned o=(unsigned)__shfl_xor((int)lm,off); if (o<lm) lm=o; }
          if (lane==0) wMinB[par][wv]=lm;
          __syncthreads();
          unsigned m0=wMinB[par][0];
          for (int w2=1;w2<4;w2++){ unsigned o=wMinB[par][w2]; if (o<m0) m0=o; }
          vhB = m0;
        }
        float vlo = __uint_as_float(vloB);
        float vhi = __uint_as_float(vhB);
        // jnp.quantile(col,0.7): aq = f32(0.7)*6143 -> exact weights
        float thr = __fadd_rn(__fmul_rn(vlo, 0.89990234375f), __fmul_rn(vhi, 0.10009765625f));
        #pragma unroll
        for (int u=0;u<RPT;u++){
          float sv = __fmul_rn(uC[u], G[u]);
          if (sv < thr){
            float rs  = __fsub_rn(__fmul_rn(R[u], G[u]), sv);
            float rsm = fmaxf(rs, 1e-12f);
            float uo  = __fdiv_rn(sv, G[u]);
            uC[u] = 0.0f;
            G[u] = __fdiv_rn(G[u], rsm);
            R[u] = __fsub_rn(R[u], uo);
          }
        }
        storecol24(uC, Ucm, k, r0);
      }
      if (k<19){
        #pragma unroll
        for (int u=0;u<RPT;u++) uC[u]=uN[u];
      }
    }
  }
  __syncthreads();

  // ---- hard rebalance: 5 iterations, 1 barrier each (fast path) ----
  int par = 0;
  #pragma unroll 1
  for (int it=0; it<5; it++){
    // phase A: per-wave colsum + zerocount publish
    #pragma unroll 1
    for (int c=0;c<20;c++){
      float vv[RPT];
      loadcol24(vv, Ucm, c, r0);
      float a=0.f; int z=0;
      #pragma unroll
      for (int u=0;u<RPT;u++){ if (vv[u]==0.0f) z++; a += __fmul_rn(vv[u], G[u]); }
      for (int off=32;off>0;off>>=1){ a += __shfl_down(a,off); z += __shfl_down(z,off); }
      if (lane==0){ accW[par][wv][c]=a; zcW[par][wv][c]=z; }
    }
    __syncthreads();
    // phase B: redundant global calc
    float s=0.f; int anyAct=0, needGen=0;
    #pragma unroll 1
    for (int c=0;c<20;c++){
      float csf = ((accW[par][0][c] + accW[par][1][c]) + accW[par][2][c]) + accW[par][3][c];
      s += fmaxf(20.0f-csf, 0.f);
      if (csf > 20.0f){
        anyAct = 1;
        int num = (int)ceilf(csf - 20.0f) + 5; if (num > 6144) num = 6144;
        int totZ = zcW[par][0][c]+zcW[par][1][c]+zcW[par][2][c]+zcW[par][3][c];
        if (num > totZ) needGen = 1;
      }
    }
    int wzero = (s == 0.0f) ? 1 : 0;
    if (anyAct && !wzero) needGen = 1;
    if (!anyAct){ par ^= 1; continue; }
    if (!needGen){
      // fast path: per column, weak = first num exact-zero rows by index; own-row updates only
      #pragma unroll 1
      for (int c=0;c<20;c++){
        float csf = ((accW[par][0][c] + accW[par][1][c]) + accW[par][2][c]) + accW[par][3][c];
        if (csf > 20.0f){
          int num = (int)ceilf(csf - 20.0f) + 5; if (num > 6144) num = 6144;
          float vv[RPT];
          loadcol24(vv, Ucm, c, r0);
          int z=0;
          #pragma unroll
          for (int u=0;u<RPT;u++) z += (vv[u]==0.0f) ? 1 : 0;
          int incz = z;
          for (int off=1;off<64;off<<=1){ int nv=__shfl_up(incz,off); if (lane>=off) incz+=nv; }
          int base = incz - z;
          for (int w2=0;w2<wv;w2++) base += zcW[par][w2][c];
          int rank = base;
          #pragma unroll
          for (int u=0;u<RPT;u++){
            if (vv[u]==0.0f){
              if (rank < num){
                float Gold = G[u];
                float t   = __fadd_rn(__fmul_rn(R[u], Gold), 1e-8f);
                float rsm = fmaxf(t, 1e-12f);
                float un  = __fdiv_rn(1e-8f, Gold);
                Ucm[c*6144+r0+u] = un;
                G[u] = __fdiv_rn(Gold, rsm);
                R[u] = __fadd_rn(R[u], un);
              }
              rank++;
            }
          }
        }
      }
      par ^= 1;
    } else {
      // general path (reference-faithful); wLs needed
      if (tid<20){
        float csf = ((accW[par][0][tid] + accW[par][1][tid]) + accW[par][2][tid]) + accW[par][3][tid];
        wLs[tid] = fmaxf(20.0f-csf,0.f) / (s + 1e-8f);
      }
      #pragma unroll 1
      for (int k=0;k<20;k++){
        float csf = ((accW[par][0][k] + accW[par][1][k]) + accW[par][2][k]) + accW[par][3][k];
        if (csf > 20.0f){
          int num = (int)ceilf(csf - 20.0f) + 5; if (num > 6144) num = 6144;
          int gpar = selCnt & 1; selCnt++;
          rebalGeneral(k, num, Ucm, G, R, wLs, hist, stb, gpar, wS, &totAllS, tid, lane, wv);
        }
      }
      par ^= 1;
    }
  }

  // ---- emit per-row scale ----
  { float4* gp = (float4*)(Gout + r0);
    #pragma unroll
    for (int q=0;q<RPT/4;q++){ float4 f; f.x=G[q*4]; f.y=G[q*4+1]; f.z=G[q*4+2]; f.w=G[q*4+3]; gp[q]=f; } }
}

// ---------------- final: materialize S (outS + SW), entropy, cs_final, x_pooled ----------------
__global__ __launch_bounds__(256) void k_final(const float* __restrict__ Ucm, const float* __restrict__ Gout,
    const float* __restrict__ xe, float* __restrict__ outXP, float* __restrict__ outS,
    float* __restrict__ SW, float* __restrict__ csfin, double* __restrict__ entAcc){
  __shared__ float Sblk[256][21];
  __shared__ float csL[20];
  __shared__ double entL[4];
  const int tid = threadIdx.x;
  const int r0 = blockIdx.x * 256;
  const int lane = tid & 63, wvq = tid >> 6;
  if (tid < 20) csL[tid]=0.f;
  __syncthreads();
  {
    const int r = r0 + tid;
    const float Gr = Gout[r];
    float sv[20]; float ent=0.f;
    #pragma unroll
    for (int c=0;c<20;c++) sv[c]=__fmul_rn(Ucm[c*6144+r], Gr);
    float4* so = (float4*)(outS + r*20);
    float4* sw = (float4*)(SW + r*20);
    #pragma unroll
    for (int q=0;q<5;q++){ float4 f; f.x=sv[q*4]; f.y=sv[q*4+1]; f.z=sv[q*4+2]; f.w=sv[q*4+3]; so[q]=f; sw[q]=f; }
    #pragma unroll
    for (int c=0;c<20;c++){ Sblk[tid][c]=sv[c]; ent += sv[c]*logf(sv[c]+1e-08f); }
    #pragma unroll
    for (int c=0;c<20;c++) atomicAdd(&csL[c], sv[c]);
    double ed = (double)ent;
    for (int off=32;off>0;off>>=1) ed += __shfl_down(ed, off);
    if (lane==0) entL[wvq]=ed;
  }
  __syncthreads();
  if (tid==0) atomicAdd(entAcc, entL[0]+entL[1]+entL[2]+entL[3]);
  if (tid<20) atomicAdd(&csfin[tid], csL[tid]);
  float acc[20];
  #pragma unroll
  for (int c=0;c<20;c++) acc[c]=0.f;
  for (int i=0;i<256;i++){
    float xv = xe[(r0+i)*256 + tid];
    #pragma unroll
    for (int c=0;c<20;c++) acc[c]=fmaf(Sblk[i][c], xv, acc[c]);
  }
  #pragma unroll
  for (int c=0;c<20;c++) atomicAdd(&outXP[c*256+tid], acc[c]);
}

// ---------------- bitmap build (dedup only) ----------------
__global__ __launch_bounds__(256) void k_bitmap(const int* __restrict__ ei,
    unsigned int* __restrict__ bitmap){
  const int e = blockIdx.x*256 + threadIdx.x;
  const int i = ei[e], j = ei[NE+e];
  unsigned bit = (unsigned)i*6144u + (unsigned)j;
  atomicOr(&bitmap[bit >> 5], 1u << (bit & 31u));
}

// ---------------- bitmap scan: T = adj@S rows (no atomics) + dedup'd edge loss ----------------
__global__ __launch_bounds__(256) void k_adjT(const unsigned* __restrict__ bitmap,
    const float* __restrict__ SW, float* __restrict__ T, double* __restrict__ edgeAcc){
  __shared__ double wsum[4];
  const int tid = threadIdx.x;
  const int lane = tid & 63, wvq = tid >> 6;
  const int rbase = blockIdx.x*64 + wvq*16;   // 96 blocks x 4 waves x 16 rows
  float eacc = 0.f;
  for (int rr=0; rr<16; rr++){
    const int i = rbase + rr;
    float Si[20];
    { const float4* sp = (const float4*)(SW + i*20);
      #pragma unroll
      for (int q=0;q<5;q++){ float4 f=sp[q]; Si[q*4]=f.x; Si[q*4+1]=f.y; Si[q*4+2]=f.z; Si[q*4+3]=f.w; } }
    float Tp[20];
    #pragma unroll
    for (int c=0;c<20;c++) Tp[c]=0.f;
    #pragma unroll
    for (int w=0; w<3; w++){
      const int wq = lane + w*64;             // word index within row, 0..191
      unsigned word = bitmap[i*192 + wq];
      while (word){
        int b = __ffs((int)word) - 1; word &= (word-1u);
        int j = wq*32 + b;
        const float4* sj = (const float4*)(SW + j*20);
        float p = 0.f;
        #pragma unroll
        for (int q=0;q<5;q++){
          float4 f = sj[q];
          Tp[q*4]+=f.x; Tp[q*4+1]+=f.y; Tp[q*4+2]+=f.z; Tp[q*4+3]+=f.w;
          p = fmaf(Si[q*4],f.x, fmaf(Si[q*4+1],f.y, fmaf(Si[q*4+2],f.z, fmaf(Si[q*4+3],f.w, p))));
        }
        float pcl = fminf(fmaxf(p,0.f),1.f);
        float lg  = fmaxf(logf(pcl),   -100.f);
        float l1  = fmaxf(log1pf(-pcl),-100.f);
        eacc += (lg - l1);
      }
    }
    float tr[20];
    #pragma unroll
    for (int c=0;c<20;c++){
      float t = Tp[c];
      for (int off=32;off>0;off>>=1) t += __shfl_down(t, off);
      tr[c]=t;
    }
    if (lane==0){
      float4* tw = (float4*)(T + i*20);
      #pragma unroll
      for (int q=0;q<5;q++){ float4 f; f.x=tr[q*4]; f.y=tr[q*4+1]; f.z=tr[q*4+2]; f.w=tr[q*4+3]; tw[q]=f; }
    }
  }
  double cd = (double)eacc;
  for (int off=32;off>0;off>>=1) cd += __shfl_down(cd, off);
  if (lane==0) wsum[wvq]=cd;
  __syncthreads();
  if (tid==0) atomicAdd(edgeAcc, wsum[0]+wsum[1]+wsum[2]+wsum[3]);
}

// ---------------- adj_pooled = S.T @ T ----------------
__global__ __launch_bounds__(400) void k_adjpool(const float* __restrict__ SW, const float* __restrict__ T,
    float* __restrict__ outAdj){
  const int tid = threadIdx.x;
  const int c = tid/20, d = tid%20;
  const int r0 = blockIdx.x*256;
  float acc=0.f;
  for (int i=0;i<256;i++) acc = fmaf(SW[(r0+i)*20+c], T[(r0+i)*20+d], acc);
  atomicAdd(&outAdj[c*20+d], acc);
}

// ---------------- all-pair sum of clamped log1p(-p) ----------------
__global__ __launch_bounds__(256) void k_link(const float* __restrict__ SW, double* __restrict__ acc){
  __shared__ float Si[256][21];
  __shared__ float Sj[256][21];
  __shared__ double wsum[4];
  const int tid = threadIdx.x;
  const int ib = blockIdx.x*256, jb = blockIdx.y*256;
  const int lane = tid & 63, wvq = tid >> 6;
  for (int idx=tid; idx<5120; idx+=256){ int r=idx/20, c=idx%20; Si[r][c]=SW[(ib+r)*20+c]; }
  for (int idx=tid; idx<5120; idx+=256){ int r=idx/20, c=idx%20; Sj[r][c]=SW[(jb+r)*20+c]; }
  __syncthreads();
  float rA[20];
  #pragma unroll
  for (int c=0;c<20;c++) rA[c]=Si[tid][c];
  float af = 0.f;
  for (int jj=0;jj<256;jj++){
    float p=0.f;
    #pragma unroll
    for (int c=0;c<20;c++) p = fmaf(rA[c], Sj[jj][c], p);
    float pcl = fminf(fmaxf(p,0.f),1.f);
    af += fmaxf(log1pf(-pcl), -100.f);
  }
  double cd = (double)af;
  for (int off=32;off>0;off>>=1) cd += __shfl_down(cd, off);
  if (lane==0) wsum[wvq]=cd;
  __syncthreads();
  if (tid==0) atomicAdd(acc, wsum[0]+wsum[1]+wsum[2]+wsum[3]);
}

// ---------------- aux scalar ----------------
__global__ void k_aux(const double* __restrict__ dAcc, const float* __restrict__ csfin, float* __restrict__ outAux){
  const double nsq = 6144.0*6144.0;
  float link = (float)(-(dAcc[0]+dAcc[1])/nsq);
  float ent  = (float)(-(dAcc[2]/6144.0));
  float s=0.f;
  for (int c=0;c<20;c++) s += fabsf(csfin[c]-307.2f);
  float bal = (s/20.0f)/307.2f;
  outAux[0] = link + 0.1f*ent + 0.5f*bal;
}

extern "C" void kernel_launch(void* const* d_in, const int* in_sizes, int n_in,
                              void* d_out, int out_size, void* d_ws, size_t ws_size,
                              hipStream_t stream) {
  const float* x   = (const float*)d_in[0];
  const int*   ei  = (const int*)d_in[1];
  // d_in[2] = lv_group_ids: dead (LV table is never 0 -> mask is identity)
  const float* W1  = (const float*)d_in[3];
  const float* b1  = (const float*)d_in[4];
  const float* W2  = (const float*)d_in[5];
  const float* b2  = (const float*)d_in[6];
  const float* W3  = (const float*)d_in[7];
  const float* b3  = (const float*)d_in[8];
  const float* We1 = (const float*)d_in[9];
  const float* be1 = (const float*)d_in[10];
  const float* We2 = (const float*)d_in[11];
  const float* be2 = (const float*)d_in[12];

  char* ws = (char*)d_ws;
  float* T        = (float*)(ws + OFF_T);
  unsigned int* bitmap = (unsigned int*)(ws + OFF_BITMAP);
  float* colsum0  = (float*)(ws + OFF_COLSUM0);
  float* csG      = (float*)(ws + OFF_CSG);
  float* csfin    = (float*)(ws + OFF_CSFIN);
  double* dAcc    = (double*)(ws + OFF_DACC);
  float* logits   = (float*)(ws + OFF_LOGITS);
  float* Ucm      = (float*)(ws + OFF_UCM);
  float* SW       = (float*)(ws + OFF_SW);
  float* xe       = (float*)(ws + OFF_XE);
  float* trow     = (float*)(ws + OFF_TROW);
  float* Gout     = (float*)(ws + OFF_GOUT);

  float* out   = (float*)d_out;
  float* outXP = out;            // 20*256
  float* outAdj= out + 5120;     // 20*20
  float* outS  = out + 5520;     // 6144*20
  float* outAux= out + 128400;   // 1

  hipMemsetAsync(d_ws, 0, (size_t)ZERO_BYTES, stream);
  hipMemsetAsync(d_out, 0, (size_t)out_size*sizeof(float), stream);

  k_mlp<<<384, 128, 0, stream>>>(x, W1,b1, W2,b2, W3,b3, logits);
  k_embed<<<384, 256, 0, stream>>>(x, We1,be1, We2,be2, xe);
  k_sm1<<<24, 256, 0, stream>>>(logits, colsum0);
  k_sm2cm<<<24, 256, 0, stream>>>(logits, colsum0, Ucm, csG);
  k_prepcm<<<24, 256, 0, stream>>>(csG, Ucm, trow);
  k_midseq<<<1, 256, 0, stream>>>(csG, trow, Ucm, Gout);
  k_bitmap<<<384, 256, 0, stream>>>(ei, bitmap);
  k_final<<<24, 256, 0, stream>>>(Ucm, Gout, xe, outXP, outS, SW, csfin, &dAcc[2]);
  k_adjT<<<96, 256, 0, stream>>>(bitmap, SW, T, &dAcc[1]);
  k_adjpool<<<24, 400, 0, stream>>>(SW, T, outAdj);
  k_link<<<dim3(24,24), 256, 0, stream>>>(SW, &dAcc[0]);
  k_aux<<<1, 1, 0, stream>>>(dAcc, csfin, outAux);
}